// Round 3
// baseline (1846.361 us; speedup 1.0000x reference)
//
#include <hip/hip_runtime.h>

#define D 256
#define K2 512          // concatenated K for the output GEMM (two supports)
#define CAP 64          // padded row stride in slots (4B each)
#define CAP_S 60        // slots staged in LDS per row (62KB limit); rows deeper spill to ovf
#define OVFCAP 16384    // overflow edge list capacity
#define BCAP 10240      // entries per bucket region (mean 8163, +23 sigma)
#define CHUNK 8192      // edges per binning block

// persistent sweep geometry
#define NW 2048         // persistent waves (512 blocks x 4)
#define RPW 25          // rows per wave (NW*RPW = 51200 >= nrows)
#define TTILES 16       // src tiles (src>>12, 2MB each)
#define SEGSTRIDE 51200 // qseg row stride (= NW*RPW)

typedef __attribute__((ext_vector_type(8))) short short8;
typedef __attribute__((ext_vector_type(4))) float f32x4;

__device__ inline ushort f2bf(float f) {
  unsigned u = __float_as_uint(f);
  unsigned r = (u + 0x7FFF + ((u >> 16) & 1)) >> 16;  // RNE
  return (ushort)r;
}
__device__ inline float bf_lo(unsigned u) { return __uint_as_float(u << 16); }
__device__ inline float bf_hi(unsigned u) { return __uint_as_float(u & 0xFFFF0000u); }

// ---------------- prep: transpose W0|W1 into Wt[n][k0..511] + zero counters/qseg ----------------
__global__ __launch_bounds__(256) void prep_kernel(const float* __restrict__ W0,
                                                   const float* __restrict__ W1,
                                                   ushort* __restrict__ Wt,
                                                   int* __restrict__ gz, int ngz) {
  if (blockIdx.x < 128) {
    const int blk = blockIdx.x;
    const float* W = (blk >> 6) ? W1 : W0;
    const int koff = (blk >> 6) ? 256 : 0;
    __shared__ float t[32][33];
    int tx = threadIdx.x & 31, ty = threadIdx.x >> 5;
    int b = blk & 63;
    int k0 = (b & 7) * 32, n0 = (b >> 3) * 32;
    for (int r = ty; r < 32; r += 8)
      t[r][tx] = W[(size_t)(k0 + r) * D + n0 + tx];
    __syncthreads();
    for (int r = ty; r < 32; r += 8)
      Wt[(size_t)(n0 + r) * K2 + koff + k0 + tx] = f2bf(t[tx][r]);
  } else {
    int nb = gridDim.x - 128;
    for (int i = (blockIdx.x - 128) * 256 + threadIdx.x; i < ngz; i += nb * 256)
      gz[i] = 0;
  }
}

// ---------------- pass A: bin edges by dst>>8 into dense bucket regions ----------------
__device__ __forceinline__ void binA_body(const int* __restrict__ src,
                                          const int* __restrict__ dst,
                                          const float* __restrict__ val, int E,
                                          int* __restrict__ gcur,
                                          int2* __restrict__ binned,
                                          int* __restrict__ ovfc, int4* __restrict__ ovf,
                                          int nbkt, int blk) {
  __shared__ int hist[200];
  __shared__ int base[200];
  const int tid = threadIdx.x;
  for (int i = tid; i < nbkt; i += 256) hist[i] = 0;
  __syncthreads();
  const int e0 = blk * CHUNK;
  const int e1 = min(E, e0 + CHUNK);
  for (int e = e0 + tid; e < e1; e += 256)
    atomicAdd(&hist[dst[e] >> 8], 1);
  __syncthreads();
  for (int i = tid; i < nbkt; i += 256) {
    int h = hist[i];
    base[i] = h ? atomicAdd(&gcur[i], h) : 0;
    hist[i] = 0;  // becomes local cursor
  }
  __syncthreads();
  for (int e = e0 + tid; e < e1; e += 256) {
    int d = dst[e];
    int s = src[e];
    int vb = __float_as_int(val[e]);
    int k = d >> 8;
    int pos = base[k] + atomicAdd(&hist[k], 1);
    if (pos < BCAP) {
      binned[(size_t)k * BCAP + pos] = make_int2(((d & 255) << 16) | s, vb);
    } else {
      int o = atomicAdd(ovfc, 1);
      if (o < OVFCAP) ovf[o] = make_int4(d, s, vb, 0);
    }
  }
}

// ---------------- fat: binA0 || binA1 || x -> bf16 convert ----------------
__global__ __launch_bounds__(256) void fat_kernel(
    const float* __restrict__ x, ushort* __restrict__ Xb, int nq,
    const int* __restrict__ src0, const int* __restrict__ dst0, const float* __restrict__ val0,
    int E0, int* __restrict__ gcur0, int2* __restrict__ binned0, int* __restrict__ ovfc0,
    int4* __restrict__ ovf0,
    const int* __restrict__ src1, const int* __restrict__ dst1, const float* __restrict__ val1,
    int E1, int* __restrict__ gcur1, int2* __restrict__ binned1, int* __restrict__ ovfc1,
    int4* __restrict__ ovf1,
    int nbkt, int nbA0, int nbA1) {
  const int bid = blockIdx.x;
  if (bid < nbA0) {
    binA_body(src0, dst0, val0, E0, gcur0, binned0, ovfc0, ovf0, nbkt, bid);
  } else if (bid < nbA0 + nbA1) {
    binA_body(src1, dst1, val1, E1, gcur1, binned1, ovfc1, ovf1, nbkt, bid - nbA0);
  } else {
    const int nxb = gridDim.x - nbA0 - nbA1;
    for (int i = (bid - nbA0 - nbA1) * 256 + threadIdx.x; i < nq; i += nxb * 256) {
      float4 v = ((const float4*)x)[i];
      ushort4 o;
      o.x = f2bf(v.x); o.y = f2bf(v.y); o.z = f2bf(v.z); o.w = f2bf(v.w);
      ((ushort4*)Xb)[i] = o;
    }
  }
}

// ---------------- pass B: bucket -> padded rows, SORTED by src + per-tile quad offsets ----------------
// Tail quads zero-filled (src 0, val +0.0 => no-op). Per-row list sorted ascending by src,
// then qseg[t][row] = first quad index whose first-edge tile (src>>12) >= t, t = 0..TTILES.
__device__ __forceinline__ void passB_body(const int2* __restrict__ binned,
                                           const int* __restrict__ gcur,
                                           uint* __restrict__ padded,
                                           unsigned char* __restrict__ qseg,
                                           int* __restrict__ ovfc, int4* __restrict__ ovf,
                                           int b) {
  __shared__ int lcnt[256];
  __shared__ uint stage[256 * CAP_S];  // 60KB
  const int tid = threadIdx.x;
  lcnt[tid] = 0;
  __syncthreads();
  const int n = min(gcur[b], BCAP);
  const int2* bp = binned + (size_t)b * BCAP;
  for (int i = tid; i < n; i += 256) {
    int2 e = bp[i];
    int dlow = (e.x >> 16) & 255;
    int s = atomicAdd(&lcnt[dlow], 1);
    if (s < CAP_S) {
      float v = __int_as_float(e.y);
      stage[dlow * CAP_S + s] = (uint)(e.x & 0xFFFF) | ((uint)f2bf(v) << 16);
    } else {
      int o = atomicAdd(ovfc, 1);
      if (o < OVFCAP) ovf[o] = make_int4((b << 8) + dlow, e.x & 0xFFFF, e.y, 0);
    }
  }
  __syncthreads();
  // thread tid owns row (b*256 + tid)
  const int row = (b << 8) + tid;
  const int written = min(lcnt[tid], CAP_S);
  uint* sp = &stage[tid * CAP_S];
  // insertion sort by src (low 16 bits)
  for (int i = 1; i < written; ++i) {
    uint key = sp[i];
    uint ks = key & 0xFFFFu;
    int j = i - 1;
    while (j >= 0 && (sp[j] & 0xFFFFu) > ks) { sp[j + 1] = sp[j]; --j; }
    sp[j + 1] = key;
  }
  const int nq = (written + 3) >> 2;
  // per-tile quad boundaries (quad assigned to tile of its first edge)
  int qp = 0;
  for (int t = 0; t <= TTILES; ++t) {
    while (qp < nq && (int)((sp[4 * qp] & 0xFFFFu) >> 12) < t) ++qp;
    qseg[t * SEGSTRIDE + row] = (unsigned char)qp;
  }
  // zero tail + flush
  for (int s = written; s < (nq << 2); ++s) sp[s] = 0;
  uint4* dp = (uint4*)(padded + ((size_t)row << 6));
  const uint4* spq = (const uint4*)sp;
  for (int q = 0; q < nq; ++q) dp[q] = spq[q];
}

__global__ __launch_bounds__(256) void passBoth(
    const int2* __restrict__ binned0, const int* __restrict__ gcur0, uint* __restrict__ padded0,
    unsigned char* __restrict__ qseg0, int* __restrict__ ovfc0, int4* __restrict__ ovf0,
    const int2* __restrict__ binned1, const int* __restrict__ gcur1, uint* __restrict__ padded1,
    unsigned char* __restrict__ qseg1, int* __restrict__ ovfc1, int4* __restrict__ ovf1,
    int nbkt) {
  if (blockIdx.x < nbkt)
    passB_body(binned0, gcur0, padded0, qseg0, ovfc0, ovf0, blockIdx.x);
  else
    passB_body(binned1, gcur1, padded1, qseg1, ovfc1, ovf1, blockIdx.x - nbkt);
}

// ---------------- persistent sweep spmm ----------------
__device__ __forceinline__ void edge_fma(uint e, const uint2* __restrict__ X2, int lane,
                                         float4& a) {
  uint2 h = X2[((e & 0xFFFFu) << 6) + lane];
  float v = __uint_as_float(e & 0xFFFF0000u);
  a.x += v * bf_lo(h.x);
  a.y += v * bf_hi(h.x);
  a.z += v * bf_lo(h.y);
  a.w += v * bf_hi(h.y);
}

// One support's tile sweep: masked branchless bodies, unrolled over RPW rows for ILP.
#define SWEEP_SUP(QSEG, PB, ACC)                                                  \
  {                                                                               \
    uint qr[RPW];                                                                 \
    _Pragma("unroll") for (int i = 0; i < RPW; ++i) {                             \
      uint r = (uint)wid + (uint)i * NW;                                          \
      qr[i] = (uint)QSEG[t * SEGSTRIDE + r] |                                     \
              ((uint)QSEG[(t + 1) * SEGSTRIDE + r] << 16);                        \
    }                                                                             \
    for (;;) {                                                                    \
      bool any = false;                                                           \
      _Pragma("unroll") for (int i = 0; i < RPW; ++i)                             \
          any |= (qr[i] & 0xFFFFu) < (qr[i] >> 16);                               \
      if (!any) break;                                                            \
      _Pragma("unroll") for (int i = 0; i < RPW; ++i) {                           \
        uint qp = qr[i] & 0xFFFFu, qe = qr[i] >> 16;                              \
        bool act = qp < qe;                                                       \
        uint midx = (((uint)wid + (uint)i * NW) << 4) + (act ? qp : 0u);          \
        uint4 m = ((const uint4*)PB)[midx];                                       \
        qr[i] += act ? 1u : 0u;                                                   \
        uint msk = act ? 0xFFFFFFFFu : 0u;                                        \
        edge_fma(m.x & msk, X2, lane, ACC[i]);                                    \
        edge_fma(m.y & msk, X2, lane, ACC[i]);                                    \
        edge_fma(m.z & msk, X2, lane, ACC[i]);                                    \
        edge_fma(m.w & msk, X2, lane, ACC[i]);                                    \
      }                                                                           \
    }                                                                             \
  }

__global__ __launch_bounds__(256, 2) void spmm_sweep(
    const ushort* __restrict__ Xb,
    const uint* __restrict__ padded0, const uint* __restrict__ padded1,
    const unsigned char* __restrict__ qseg0, const unsigned char* __restrict__ qseg1,
    ushort* __restrict__ Y, int nrows) {
  const int wid = blockIdx.x * 4 + (threadIdx.x >> 6);
  const int lane = threadIdx.x & 63;
  const uint2* X2 = (const uint2*)Xb;
  float4 acc0[RPW], acc1[RPW];
#pragma unroll
  for (int i = 0; i < RPW; ++i) {
    acc0[i] = make_float4(0.f, 0.f, 0.f, 0.f);
    acc1[i] = make_float4(0.f, 0.f, 0.f, 0.f);
  }
  for (int t = 0; t < TTILES; ++t) {
    SWEEP_SUP(qseg0, padded0, acc0);
    SWEEP_SUP(qseg1, padded1, acc1);
  }
  // epilogue: write Y rows
#pragma unroll
  for (int i = 0; i < RPW; ++i) {
    int r = wid + i * NW;
    if (r < nrows) {
      ushort4 o0, o1;
      o0.x = f2bf(acc0[i].x); o0.y = f2bf(acc0[i].y);
      o0.z = f2bf(acc0[i].z); o0.w = f2bf(acc0[i].w);
      o1.x = f2bf(acc1[i].x); o1.y = f2bf(acc1[i].y);
      o1.z = f2bf(acc1[i].z); o1.w = f2bf(acc1[i].w);
      *(ushort4*)(Y + (size_t)r * K2 + 4 * lane) = o0;
      *(ushort4*)(Y + (size_t)r * K2 + 256 + 4 * lane) = o1;
    }
  }
}

// ---------------- overflow: serialized RMW into Y (expected 0 entries) ----------------
__global__ void ovf_serial(const int* __restrict__ ovfc0, const int4* __restrict__ ovf0,
                           const int* __restrict__ ovfc1, const int4* __restrict__ ovf1,
                           const ushort* __restrict__ Xb, ushort* __restrict__ Y) {
  int n0 = min(*ovfc0, OVFCAP);
  int n1 = min(*ovfc1, OVFCAP);
  const int tid = threadIdx.x;
  for (int i = 0; i < n0 + n1; ++i) {
    int4 r = (i < n0) ? ovf0[i] : ovf1[i - n0];
    int koff = (i < n0) ? 0 : 256;
    float v = __int_as_float(r.z);
    size_t yo = (size_t)r.x * K2 + koff + tid;
    float y = __uint_as_float((uint)Y[yo] << 16);
    float xv = __uint_as_float((uint)Xb[(size_t)r.y * D + tid] << 16);
    Y[yo] = f2bf(y + v * xv);
    __syncthreads();  // serialize entries (same-row collisions)
  }
}

// ---------------- output GEMM: out = relu(Y[M,512] @ Wt[256,512]^T + b) ----------------
__global__ __launch_bounds__(256) void gemm_out(const ushort* __restrict__ Y,
                                                const ushort* __restrict__ Wt,
                                                float* __restrict__ out,
                                                const float* __restrict__ bias,
                                                int M, int mtiles) {
  __shared__ ushort As[128 * 40];
  __shared__ ushort Bs[128 * 40];
  const int tid = threadIdx.x;
  const int blk = blockIdx.x;
  const int bm = (blk % mtiles) * 128;
  const int bn = (blk / mtiles) * 128;
  const int wave = tid >> 6, lane = tid & 63;
  const int wm = wave & 1, wn = wave >> 1;
  const int lr = lane & 15;
  const int kg = lane >> 4;
  f32x4 acc[4][4];
#pragma unroll
  for (int m = 0; m < 4; ++m)
#pragma unroll
    for (int n = 0; n < 4; ++n) acc[m][n] = (f32x4){0.f, 0.f, 0.f, 0.f};

  for (int k0 = 0; k0 < K2; k0 += 32) {
    __syncthreads();
#pragma unroll
    for (int c = 0; c < 2; ++c) {
      int linear = c * 256 + tid;
      int row = linear >> 2;
      int part = linear & 3;
      int gr = bm + row;
      uint4 a4 = make_uint4(0u, 0u, 0u, 0u);
      if (gr < M) a4 = *(const uint4*)(Y + (size_t)gr * K2 + k0 + part * 8);
      *(uint4*)&As[row * 40 + part * 8] = a4;
    }
#pragma unroll
    for (int c = 0; c < 2; ++c) {
      int linear = c * 256 + tid;
      int row = linear >> 2;
      int part = linear & 3;
      uint4 w4 = *(const uint4*)(Wt + (size_t)(bn + row) * K2 + k0 + part * 8);
      *(uint4*)&Bs[row * 40 + part * 8] = w4;
    }
    __syncthreads();
    short8 af[4], bfr[4];
#pragma unroll
    for (int m = 0; m < 4; ++m)
      af[m] = *(const short8*)&As[(wm * 64 + m * 16 + lr) * 40 + kg * 8];
#pragma unroll
    for (int n = 0; n < 4; ++n)
      bfr[n] = *(const short8*)&Bs[(wn * 64 + n * 16 + lr) * 40 + kg * 8];
#pragma unroll
    for (int m = 0; m < 4; ++m)
#pragma unroll
      for (int n = 0; n < 4; ++n)
        acc[m][n] = __builtin_amdgcn_mfma_f32_16x16x32_bf16(af[m], bfr[n], acc[m][n], 0, 0, 0);
  }

#pragma unroll
  for (int m = 0; m < 4; ++m)
#pragma unroll
    for (int j = 0; j < 4; ++j) {
      int gr = bm + wm * 64 + m * 16 + kg * 4 + j;
      if (gr < M) {
#pragma unroll
        for (int n = 0; n < 4; ++n) {
          int gc = bn + wn * 64 + n * 16 + lr;
          out[(size_t)gr * D + gc] = fmaxf(acc[m][n][j] + bias[gc], 0.f);
        }
      }
    }
}

extern "C" void kernel_launch(void* const* d_in, const int* in_sizes, int n_in,
                              void* d_out, int out_size, void* d_ws, size_t ws_size,
                              hipStream_t stream) {
  const float* x    = (const float*)d_in[0];
  const float* W0   = (const float*)d_in[1];
  const float* W1   = (const float*)d_in[2];
  const float* b    = (const float*)d_in[3];
  const int*   src0 = (const int*)d_in[4];
  const int*   dst0 = (const int*)d_in[5];
  const float* val0 = (const float*)d_in[6];
  const int*   src1 = (const int*)d_in[7];
  const int*   dst1 = (const int*)d_in[8];
  const float* val1 = (const float*)d_in[9];
  float* out = (float*)d_out;

  const int N  = in_sizes[0] / D;       // 50000 (< 65536: src packs in 16 bits)
  const int E0 = in_sizes[4];
  const int E1 = in_sizes[7];
  const int nbkt = (N + 255) >> 8;      // 196 buckets of 256 rows
  const int nrows = nbkt << 8;          // 50176 padded rows (<= NW*RPW = 51200)

  const int mtiles = (N + 127) / 128;           // 391
  const int NGB = mtiles * 2;                   // 782 gemm blocks (N=256 -> 2 n-tiles)
  const int nbA0 = (E0 + CHUNK - 1) / CHUNK;    // 196
  const int nbA1 = (E1 + CHUNK - 1) / CHUNK;
  const int NXB = 224;                          // x->bf16 convert blocks

  // ---- workspace layout (~105 MB; Y overlays dead binned region) ----
  size_t off = 0;
  auto alloc = [&](size_t bytes) -> void* {
    void* p = (char*)d_ws + off;
    off = (off + bytes + 255) & ~(size_t)255;
    return p;
  };
  ushort* Xb      = (ushort*)alloc((size_t)N * D * 2);        // 25.6 MB
  ushort* Wt      = (ushort*)alloc((size_t)D * K2 * 2);       // 0.26 MB
  uint*   padded0 = (uint*)alloc((size_t)nrows * CAP * 4);    // 12.85 MB
  uint*   padded1 = (uint*)alloc((size_t)nrows * CAP * 4);    // 12.85 MB
  // gz region: gcur/ovfc counters + both qseg arrays (all zeroed by prep)
  const int nqsegB = 2 * (TTILES + 1) * SEGSTRIDE;            // bytes, 1.74 MB
  int*    gzall   = (int*)alloc((size_t)(2 * nbkt + 2) * 4 + nqsegB);
  int4*   ovf0    = (int4*)alloc((size_t)OVFCAP * 16);
  int4*   ovf1    = (int4*)alloc((size_t)OVFCAP * 16);
  int2*   binned0 = (int2*)alloc((size_t)nbkt * BCAP * 8);    // 16.05 MB
  int2*   binned1 = (int2*)alloc((size_t)nbkt * BCAP * 8);    // 16.05 MB
  ushort* Y       = (ushort*)binned0;  // 51.4 MB; binned dead after passBoth

  int* gcur0 = gzall;
  int* gcur1 = gzall + nbkt;
  int* ovfc0 = gzall + 2 * nbkt;
  int* ovfc1 = gzall + 2 * nbkt + 1;
  unsigned char* qseg0 = (unsigned char*)(gzall + 2 * nbkt + 2);
  unsigned char* qseg1 = qseg0 + (TTILES + 1) * SEGSTRIDE;
  const int ngz = (2 * nbkt + 2) + nqsegB / 4;

  // 1. prep: Wcat transpose + zero counters/qseg
  prep_kernel<<<192, 256, 0, stream>>>(W0, W1, Wt, gzall, ngz);
  // 2. fat: binA0 || binA1 || x->bf16
  fat_kernel<<<nbA0 + nbA1 + NXB, 256, 0, stream>>>(
      x, Xb, N * D / 4,
      src0, dst0, val0, E0, gcur0, binned0, ovfc0, ovf0,
      src1, dst1, val1, E1, gcur1, binned1, ovfc1, ovf1,
      nbkt, nbA0, nbA1);
  // 3. passBoth: binned -> sorted padded rows + per-tile quad offsets
  passBoth<<<2 * nbkt, 256, 0, stream>>>(binned0, gcur0, padded0, qseg0, ovfc0, ovf0,
                                         binned1, gcur1, padded1, qseg1, ovfc1, ovf1, nbkt);
  // 4. persistent lockstep sweep: Y[:,0:256] = A0 @ Xb ; Y[:,256:512] = A1 @ Xb
  spmm_sweep<<<NW / 4, 256, 0, stream>>>(Xb, padded0, padded1, qseg0, qseg1, Y, nrows);
  // 5. overflow slow path (expected empty), serialized RMW into Y
  ovf_serial<<<1, 256, 0, stream>>>(ovfc0, ovf0, ovfc1, ovf1, Xb, Y);
  // 6. output GEMM: out = relu(Y @ [W0;W1]^T + b)
  gemm_out<<<NGB, 256, 0, stream>>>(Y, Wt, out, b, N, mtiles);
}

// Round 4
// 705.704 us; speedup vs baseline: 2.6163x; 2.6163x over previous
//
#include <hip/hip_runtime.h>

#define D 256
#define CAP 64          // padded row stride in slots (4B each)
#define CAP_S 60        // slots staged in LDS per row (62KB limit); rows deeper spill to ovf
#define OVFCAP 16384    // overflow edge list capacity
#define BCAP 9472       // entries per bucket region (mean 8163, +14 sigma; excess -> ovf)
#define CHUNK 8192      // edges per binning block

// persistent lockstep sweep geometry
#define NW 4096         // persistent waves (1024 blocks x 4, 4 blocks/CU)
#define RPW 13          // rows per wave (NW*RPW = 53248 >= 50176 padded rows)
#define TTILES 13       // src tiles (src>>12): 4096 rows x 512B = 2MB of H per tile
#define SEGSTRIDE 53248 // qseg row stride (= NW*RPW)

typedef __attribute__((ext_vector_type(8))) short short8;
typedef __attribute__((ext_vector_type(4))) float f32x4;

__device__ inline ushort f2bf(float f) {
  unsigned u = __float_as_uint(f);
  unsigned r = (u + 0x7FFF + ((u >> 16) & 1)) >> 16;  // RNE
  return (ushort)r;
}
__device__ inline float bf_lo(unsigned u) { return __uint_as_float(u << 16); }
__device__ inline float bf_hi(unsigned u) { return __uint_as_float(u & 0xFFFF0000u); }

// ---------------- prep: transpose W0/W1 (blocks 0..127) + zero gz region ----------------
__global__ __launch_bounds__(256) void prep_kernel(const float* __restrict__ W0,
                                                   const float* __restrict__ W1,
                                                   ushort* __restrict__ Wt0,
                                                   ushort* __restrict__ Wt1,
                                                   int* __restrict__ gz, int ngz) {
  if (blockIdx.x < 128) {
    const int blk = blockIdx.x;
    const float* W = (blk >> 6) ? W1 : W0;
    ushort* Wt = (blk >> 6) ? Wt1 : Wt0;
    __shared__ float t[32][33];
    int tx = threadIdx.x & 31, ty = threadIdx.x >> 5;
    int k0 = (blk & 7) * 32, n0 = ((blk >> 3) & 7) * 32;
    for (int r = ty; r < 32; r += 8)
      t[r][tx] = W[(size_t)(k0 + r) * D + n0 + tx];
    __syncthreads();
    for (int r = ty; r < 32; r += 8)
      Wt[(size_t)(n0 + r) * D + k0 + tx] = f2bf(t[tx][r]);
  } else {
    int nb = gridDim.x - 128;
    for (int i = (blockIdx.x - 128) * 256 + threadIdx.x; i < ngz; i += nb * 256)
      gz[i] = 0;
  }
}

// ---------------- GEMM body: C_bf16[M,256] = bf16(A_f32) @ Bt ----------------
__device__ __forceinline__ void gemm_body(const float* __restrict__ A,
                                          const ushort* __restrict__ Bt,
                                          ushort* __restrict__ C, int M,
                                          int blk, int mtiles) {
  __shared__ ushort As[128 * 40];
  __shared__ ushort Bs[128 * 40];
  const int tid = threadIdx.x;
  const int bm = (blk % mtiles) * 128;
  const int bn = (blk / mtiles) * 128;
  const int wave = tid >> 6, lane = tid & 63;
  const int wm = wave & 1, wn = wave >> 1;
  const int lr = lane & 15;
  const int kg = lane >> 4;
  f32x4 acc[4][4];
#pragma unroll
  for (int m = 0; m < 4; ++m)
#pragma unroll
    for (int n = 0; n < 4; ++n) acc[m][n] = (f32x4){0.f, 0.f, 0.f, 0.f};

  for (int k0 = 0; k0 < D; k0 += 32) {
    __syncthreads();
#pragma unroll
    for (int c = 0; c < 4; ++c) {
      int linear = c * 256 + tid;
      int row = linear >> 3;
      int f4 = linear & 7;
      int gr = bm + row;
      float4 a = (gr < M) ? *(const float4*)(A + (size_t)gr * D + k0 + f4 * 4)
                          : make_float4(0.f, 0.f, 0.f, 0.f);
      ushort4 o;
      o.x = f2bf(a.x); o.y = f2bf(a.y); o.z = f2bf(a.z); o.w = f2bf(a.w);
      *(ushort4*)&As[row * 40 + f4 * 4] = o;
    }
#pragma unroll
    for (int c = 0; c < 2; ++c) {
      int linear = c * 256 + tid;
      int row = linear >> 2;
      int part = linear & 3;
      uint4 w4 = *(const uint4*)(Bt + (size_t)(bn + row) * D + k0 + part * 8);
      *(uint4*)&Bs[row * 40 + part * 8] = w4;
    }
    __syncthreads();
    short8 af[4], bfr[4];
#pragma unroll
    for (int m = 0; m < 4; ++m)
      af[m] = *(const short8*)&As[(wm * 64 + m * 16 + lr) * 40 + kg * 8];
#pragma unroll
    for (int n = 0; n < 4; ++n)
      bfr[n] = *(const short8*)&Bs[(wn * 64 + n * 16 + lr) * 40 + kg * 8];
#pragma unroll
    for (int m = 0; m < 4; ++m)
#pragma unroll
      for (int n = 0; n < 4; ++n)
        acc[m][n] = __builtin_amdgcn_mfma_f32_16x16x32_bf16(af[m], bfr[n], acc[m][n], 0, 0, 0);
  }

#pragma unroll
  for (int m = 0; m < 4; ++m)
#pragma unroll
    for (int j = 0; j < 4; ++j) {
      int gr = bm + wm * 64 + m * 16 + kg * 4 + j;
      if (gr < M) {
#pragma unroll
        for (int n = 0; n < 4; ++n) {
          int gc = bn + wn * 64 + n * 16 + lr;
          C[(size_t)gr * D + gc] = f2bf(acc[m][n][j]);
        }
      }
    }
}

// ---------------- pass A: bin edges by dst>>8 into dense bucket regions ----------------
__device__ __forceinline__ void binA_body(const int* __restrict__ src,
                                          const int* __restrict__ dst,
                                          const float* __restrict__ val, int E,
                                          int* __restrict__ gcur,
                                          int2* __restrict__ binned,
                                          int* __restrict__ ovfc, int4* __restrict__ ovf,
                                          int nbkt, int blk) {
  __shared__ int hist[200];
  __shared__ int base[200];
  const int tid = threadIdx.x;
  for (int i = tid; i < nbkt; i += 256) hist[i] = 0;
  __syncthreads();
  const int e0 = blk * CHUNK;
  const int e1 = min(E, e0 + CHUNK);
  for (int e = e0 + tid; e < e1; e += 256)
    atomicAdd(&hist[dst[e] >> 8], 1);
  __syncthreads();
  for (int i = tid; i < nbkt; i += 256) {
    int h = hist[i];
    base[i] = h ? atomicAdd(&gcur[i], h) : 0;
    hist[i] = 0;  // becomes local cursor
  }
  __syncthreads();
  for (int e = e0 + tid; e < e1; e += 256) {
    int d = dst[e];
    int s = src[e];
    int vb = __float_as_int(val[e]);
    int k = d >> 8;
    int pos = base[k] + atomicAdd(&hist[k], 1);
    if (pos < BCAP) {
      binned[(size_t)k * BCAP + pos] = make_int2(((d & 255) << 16) | s, vb);
    } else {
      int o = atomicAdd(ovfc, 1);
      if (o < OVFCAP) ovf[o] = make_int4(d, s, vb, 0);
    }
  }
}

// ---------------- fatA2: binA0 || binA1 || gemm0 -> H0 || gemm1 -> H1 ----------------
__global__ __launch_bounds__(256) void fatA2(
    const float* __restrict__ A, const ushort* __restrict__ Bt0, const ushort* __restrict__ Bt1,
    ushort* __restrict__ H0, ushort* __restrict__ H1, int M, int mtiles,
    const int* __restrict__ src0, const int* __restrict__ dst0, const float* __restrict__ val0,
    int E0, int* __restrict__ gcur0, int2* __restrict__ binned0, int* __restrict__ ovfc0,
    int4* __restrict__ ovf0,
    const int* __restrict__ src1, const int* __restrict__ dst1, const float* __restrict__ val1,
    int E1, int* __restrict__ gcur1, int2* __restrict__ binned1, int* __restrict__ ovfc1,
    int4* __restrict__ ovf1,
    int nbkt, int nbA0, int nbA1, int NGB) {
  const int bid = blockIdx.x;
  if (bid < nbA0)
    binA_body(src0, dst0, val0, E0, gcur0, binned0, ovfc0, ovf0, nbkt, bid);
  else if (bid < nbA0 + nbA1)
    binA_body(src1, dst1, val1, E1, gcur1, binned1, ovfc1, ovf1, nbkt, bid - nbA0);
  else if (bid < nbA0 + nbA1 + NGB)
    gemm_body(A, Bt0, H0, M, bid - nbA0 - nbA1, mtiles);
  else
    gemm_body(A, Bt1, H1, M, bid - nbA0 - nbA1 - NGB, mtiles);
}

// ---------------- pass B: bucket -> padded rows SORTED by src + per-tile quad offsets ----
// Tail quads zero-filled (src 0, val +0.0 => no-op). Per-row list sorted ascending by src;
// qseg[t][row] = first quad whose first-edge tile (src>>12) >= t, t = 0..TTILES.
__device__ __forceinline__ void passB_body(const int2* __restrict__ binned,
                                           const int* __restrict__ gcur,
                                           uint* __restrict__ padded,
                                           unsigned char* __restrict__ qseg,
                                           int* __restrict__ ovfc, int4* __restrict__ ovf,
                                           int b) {
  __shared__ int lcnt[256];
  __shared__ uint stage[256 * CAP_S];  // 60KB
  const int tid = threadIdx.x;
  lcnt[tid] = 0;
  __syncthreads();
  const int n = min(gcur[b], BCAP);
  const int2* bp = binned + (size_t)b * BCAP;
  for (int i = tid; i < n; i += 256) {
    int2 e = bp[i];
    int dlow = (e.x >> 16) & 255;
    int s = atomicAdd(&lcnt[dlow], 1);
    if (s < CAP_S) {
      float v = __int_as_float(e.y);
      stage[dlow * CAP_S + s] = (uint)(e.x & 0xFFFF) | ((uint)f2bf(v) << 16);
    } else {
      int o = atomicAdd(ovfc, 1);
      if (o < OVFCAP) ovf[o] = make_int4((b << 8) + dlow, e.x & 0xFFFF, e.y, 0);
    }
  }
  __syncthreads();
  // thread tid owns row (b*256 + tid)
  const int row = (b << 8) + tid;
  const int written = min(lcnt[tid], CAP_S);
  uint* sp = &stage[tid * CAP_S];
  // insertion sort by src (low 16 bits)
  for (int i = 1; i < written; ++i) {
    uint key = sp[i];
    uint ks = key & 0xFFFFu;
    int j = i - 1;
    while (j >= 0 && (sp[j] & 0xFFFFu) > ks) { sp[j + 1] = sp[j]; --j; }
    sp[j + 1] = key;
  }
  const int nq = (written + 3) >> 2;
  // per-tile quad boundaries (quad assigned to tile of its first edge)
  int qp = 0;
  for (int t = 0; t <= TTILES; ++t) {
    while (qp < nq && (int)((sp[4 * qp] & 0xFFFFu) >> 12) < t) ++qp;
    qseg[(size_t)t * SEGSTRIDE + row] = (unsigned char)qp;
  }
  // zero tail + flush
  for (int s = written; s < (nq << 2); ++s) sp[s] = 0;
  uint4* dp = (uint4*)(padded + ((size_t)row << 6));
  const uint4* spq = (const uint4*)sp;
  for (int q = 0; q < nq; ++q) dp[q] = spq[q];
}

__global__ __launch_bounds__(256) void passBoth(
    const int2* __restrict__ binned0, const int* __restrict__ gcur0, uint* __restrict__ padded0,
    unsigned char* __restrict__ qseg0, int* __restrict__ ovfc0, int4* __restrict__ ovf0,
    const int2* __restrict__ binned1, const int* __restrict__ gcur1, uint* __restrict__ padded1,
    unsigned char* __restrict__ qseg1, int* __restrict__ ovfc1, int4* __restrict__ ovf1,
    int nbkt) {
  if (blockIdx.x < nbkt)
    passB_body(binned0, gcur0, padded0, qseg0, ovfc0, ovf0, blockIdx.x);
  else
    passB_body(binned1, gcur1, padded1, qseg1, ovfc1, ovf1, blockIdx.x - nbkt);
}

// ---------------- persistent lockstep sweep ----------------
__device__ __forceinline__ void edge_fma(uint e, const uint2* __restrict__ H2, int lane,
                                         float4& a) {
  uint2 h = H2[((size_t)(e & 0xFFFFu) << 6) + lane];
  float v = __uint_as_float(e & 0xFFFF0000u);
  a.x += v * bf_lo(h.x);
  a.y += v * bf_hi(h.x);
  a.z += v * bf_lo(h.y);
  a.w += v * bf_hi(h.y);
}

__device__ __forceinline__ void sweep_support(const ushort* __restrict__ H,
                                              const uint* __restrict__ padded,
                                              const unsigned char* __restrict__ qseg,
                                              int wid, int lane, float4* acc) {
  const uint2* H2 = (const uint2*)H;
  for (int t = 0; t < TTILES; ++t) {
    // hoist all row bounds for this tile (26 independent byte loads -> MLP)
    uint bnd[RPW];
#pragma unroll
    for (int i = 0; i < RPW; ++i) {
      uint r = (uint)wid + (uint)i * NW;
      bnd[i] = (uint)qseg[(size_t)t * SEGSTRIDE + r] |
               ((uint)qseg[(size_t)(t + 1) * SEGSTRIDE + r] << 16);
    }
#pragma unroll
    for (int i = 0; i < RPW; ++i) {
      uint q = bnd[i] & 0xFFFFu, qe = bnd[i] >> 16;
      if (q < qe) {
        uint r = (uint)wid + (uint)i * NW;
        const uint4* mp = (const uint4*)(padded + ((size_t)r << 6));
        for (; q < qe; ++q) {   // wave-uniform trip count: no masked waste
          uint4 m = mp[q];
          edge_fma(m.x, H2, lane, acc[i]);
          edge_fma(m.y, H2, lane, acc[i]);
          edge_fma(m.z, H2, lane, acc[i]);
          edge_fma(m.w, H2, lane, acc[i]);
        }
      }
    }
  }
}

__global__ __launch_bounds__(256, 4) void spmm_sweep(
    const ushort* __restrict__ H0, const ushort* __restrict__ H1,
    const uint* __restrict__ padded0, const uint* __restrict__ padded1,
    const unsigned char* __restrict__ qseg0, const unsigned char* __restrict__ qseg1,
    float* __restrict__ out, const float* __restrict__ bias,
    const int* __restrict__ rowflag, int N) {
  const int wid = blockIdx.x * 4 + (threadIdx.x >> 6);
  const int lane = threadIdx.x & 63;
  float4 acc[RPW];  // shared across both supports: 52 VGPRs
#pragma unroll
  for (int i = 0; i < RPW; ++i) acc[i] = make_float4(0.f, 0.f, 0.f, 0.f);
  sweep_support(H0, padded0, qseg0, wid, lane, acc);
  sweep_support(H1, padded1, qseg1, wid, lane, acc);
  float4 bb = ((const float4*)bias)[lane];
#pragma unroll
  for (int i = 0; i < RPW; ++i) {
    int r = wid + i * NW;
    if (r < N) {
      float4* op = (float4*)(out + (size_t)r * D) + lane;
      float4 base = make_float4(0.f, 0.f, 0.f, 0.f);
      if (rowflag[r]) base = *op;  // overflow contributions pre-accumulated
      float4 o;
      o.x = fmaxf(acc[i].x + bb.x + base.x, 0.f);
      o.y = fmaxf(acc[i].y + bb.y + base.y, 0.f);
      o.z = fmaxf(acc[i].z + bb.z + base.z, 0.f);
      o.w = fmaxf(acc[i].w + bb.w + base.w, 0.f);
      *op = o;
    }
  }
}

// ---------------- overflow cleanup (expected 0 entries) ----------------
__global__ void ovf_zero(const int* __restrict__ ovfc0, const int4* __restrict__ ovf0,
                         const int* __restrict__ ovfc1, const int4* __restrict__ ovf1,
                         float* __restrict__ out, int* __restrict__ rowflag) {
  int n0 = min(*ovfc0, OVFCAP);
  int n1 = min(*ovfc1, OVFCAP);
  int w = (blockIdx.x * blockDim.x + threadIdx.x) >> 6;
  int lane = threadIdx.x & 63;
  int nw = (gridDim.x * blockDim.x) >> 6;
  for (int i = w; i < n0 + n1; i += nw) {
    int d = (i < n0) ? ovf0[i].x : ovf1[i - n0].x;
    if (lane == 0) rowflag[d] = 1;
    ((float4*)(out + (size_t)d * D))[lane] = make_float4(0.f, 0.f, 0.f, 0.f);
  }
}

__global__ void overflow_add(const int* __restrict__ ovfc, const int4* __restrict__ ovf,
                             const ushort* __restrict__ H, float* __restrict__ out) {
  int n = min(*ovfc, OVFCAP);
  int w = (blockIdx.x * blockDim.x + threadIdx.x) >> 6;
  int lane = threadIdx.x & 63;
  int nw = (gridDim.x * blockDim.x) >> 6;
  for (int i = w; i < n; i += nw) {
    int4 r = ovf[i];
    uint2 h = *((const uint2*)(H + (size_t)r.y * D) + lane);
    float v = __int_as_float(r.z);
    float* op = out + (size_t)r.x * D + (lane << 2);
    unsafeAtomicAdd(op + 0, v * bf_lo(h.x));
    unsafeAtomicAdd(op + 1, v * bf_hi(h.x));
    unsafeAtomicAdd(op + 2, v * bf_lo(h.y));
    unsafeAtomicAdd(op + 3, v * bf_hi(h.y));
  }
}

extern "C" void kernel_launch(void* const* d_in, const int* in_sizes, int n_in,
                              void* d_out, int out_size, void* d_ws, size_t ws_size,
                              hipStream_t stream) {
  const float* x    = (const float*)d_in[0];
  const float* W0   = (const float*)d_in[1];
  const float* W1   = (const float*)d_in[2];
  const float* b    = (const float*)d_in[3];
  const int*   src0 = (const int*)d_in[4];
  const int*   dst0 = (const int*)d_in[5];
  const float* val0 = (const float*)d_in[6];
  const int*   src1 = (const int*)d_in[7];
  const int*   dst1 = (const int*)d_in[8];
  const float* val1 = (const float*)d_in[9];
  float* out = (float*)d_out;

  const int N  = in_sizes[0] / D;       // 50000 (< 65536: src packs in 16 bits)
  const int E0 = in_sizes[4];
  const int E1 = in_sizes[7];
  const int nbkt = (N + 255) >> 8;      // 196 buckets of 256 rows
  const int nrows = nbkt << 8;          // 50176 padded rows (<= NW*RPW = 53248)

  const int mtiles = (N + 127) / 128;           // 391
  const int NGB = mtiles * 2;                   // 782 gemm blocks per support
  const int nbA0 = (E0 + CHUNK - 1) / CHUNK;    // 196
  const int nbA1 = (E1 + CHUNK - 1) / CHUNK;

  // ---- workspace layout (~109 MB) ----
  size_t off = 0;
  auto alloc = [&](size_t bytes) -> void* {
    void* p = (char*)d_ws + off;
    off = (off + bytes + 255) & ~(size_t)255;
    return p;
  };
  ushort* H0      = (ushort*)alloc((size_t)N * D * 2);        // 25.6 MB
  ushort* H1      = (ushort*)alloc((size_t)N * D * 2);        // 25.6 MB
  ushort* Wt0     = (ushort*)alloc((size_t)D * D * 2);
  ushort* Wt1     = (ushort*)alloc((size_t)D * D * 2);
  uint*   padded0 = (uint*)alloc((size_t)nrows * CAP * 4);    // 12.85 MB
  uint*   padded1 = (uint*)alloc((size_t)nrows * CAP * 4);    // 12.85 MB
  // gz region (all zeroed by prep): counters + rowflag + both qseg arrays
  const size_t qsegB = (size_t)2 * (TTILES + 1) * SEGSTRIDE;  // 1.49 MB
  const size_t gzB   = (size_t)(2 * nbkt + 2 + nrows) * 4 + qsegB;
  int*    gzall   = (int*)alloc(gzB);
  int4*   ovf0    = (int4*)alloc((size_t)OVFCAP * 16);
  int4*   ovf1    = (int4*)alloc((size_t)OVFCAP * 16);
  int2*   binned0 = (int2*)alloc((size_t)nbkt * BCAP * 8);    // 14.85 MB
  int2*   binned1 = (int2*)alloc((size_t)nbkt * BCAP * 8);    // 14.85 MB

  int* gcur0   = gzall;
  int* gcur1   = gzall + nbkt;
  int* ovfc0   = gzall + 2 * nbkt;
  int* ovfc1   = gzall + 2 * nbkt + 1;
  int* rowflag = gzall + 2 * nbkt + 2;
  unsigned char* qseg0 = (unsigned char*)(rowflag + nrows);
  unsigned char* qseg1 = qseg0 + (size_t)(TTILES + 1) * SEGSTRIDE;
  const int ngz = (int)(gzB / 4);

  // 1. prep: W transposes + zero counters/rowflag/qseg
  prep_kernel<<<192, 256, 0, stream>>>(W0, W1, Wt0, Wt1, gzall, ngz);
  // 2. fatA2: binA0 || binA1 || gemm0 -> H0 || gemm1 -> H1
  fatA2<<<nbA0 + nbA1 + 2 * NGB, 256, 0, stream>>>(
      x, Wt0, Wt1, H0, H1, N, mtiles,
      src0, dst0, val0, E0, gcur0, binned0, ovfc0, ovf0,
      src1, dst1, val1, E1, gcur1, binned1, ovfc1, ovf1,
      nbkt, nbA0, nbA1, NGB);
  // 3. passBoth: binned -> src-sorted padded rows + per-tile quad offsets
  passBoth<<<2 * nbkt, 256, 0, stream>>>(binned0, gcur0, padded0, qseg0, ovfc0, ovf0,
                                         binned1, gcur1, padded1, qseg1, ovfc1, ovf1, nbkt);
  // 4. overflow slow path (expected empty): zero touched rows + flag, then add
  ovf_zero<<<16, 256, 0, stream>>>(ovfc0, ovf0, ovfc1, ovf1, out, rowflag);
  overflow_add<<<16, 256, 0, stream>>>(ovfc0, ovf0, H0, out);
  overflow_add<<<16, 256, 0, stream>>>(ovfc1, ovf1, H1, out);
  // 5. persistent lockstep sweep: out = relu(A0@H0 + A1@H1 + b [+ overflow])
  spmm_sweep<<<NW / 4, 256, 0, stream>>>(H0, H1, padded0, padded1, qseg0, qseg1,
                                         out, b, rowflag, N);
}

// Round 5
// 693.852 us; speedup vs baseline: 2.6610x; 1.0171x over previous
//
#include <hip/hip_runtime.h>

#define D 256
#define CAP 64          // padded row stride in slots (4B each)
#define CAP_S 60        // slots staged in LDS per row (62KB limit); rows deeper spill to ovf
#define OVFCAP 16384    // overflow edge list capacity
#define BCAP 9472       // entries per bucket region (mean 8163, +14 sigma; excess -> ovf)
#define CHUNK 8192      // edges per binning block

// persistent lockstep sweep geometry
#define NW 4096         // persistent waves (1024 blocks x 4, 4 blocks/CU -> all resident)
#define RPW 13          // rows per wave (NW*RPW = 53248 >= 50176 padded rows)
#define TTILES 8        // src tiles: 6250 rows x 512B = 3.2MB of H per tile (< 4MB L2/XCD)
#define SEGSTRIDE 53248 // qseg row stride (= NW*RPW)

typedef __attribute__((ext_vector_type(8))) short short8;
typedef __attribute__((ext_vector_type(4))) float f32x4;

__device__ inline ushort f2bf(float f) {
  unsigned u = __float_as_uint(f);
  unsigned r = (u + 0x7FFF + ((u >> 16) & 1)) >> 16;  // RNE
  return (ushort)r;
}
__device__ inline float bf_lo(unsigned u) { return __uint_as_float(u << 16); }
__device__ inline float bf_hi(unsigned u) { return __uint_as_float(u & 0xFFFF0000u); }

// ---------------- prep: transpose W0/W1 (blocks 0..127) + zero gz region ----------------
__global__ __launch_bounds__(256) void prep_kernel(const float* __restrict__ W0,
                                                   const float* __restrict__ W1,
                                                   ushort* __restrict__ Wt0,
                                                   ushort* __restrict__ Wt1,
                                                   int* __restrict__ gz, int ngz) {
  if (blockIdx.x < 128) {
    const int blk = blockIdx.x;
    const float* W = (blk >> 6) ? W1 : W0;
    ushort* Wt = (blk >> 6) ? Wt1 : Wt0;
    __shared__ float t[32][33];
    int tx = threadIdx.x & 31, ty = threadIdx.x >> 5;
    int k0 = (blk & 7) * 32, n0 = ((blk >> 3) & 7) * 32;
    for (int r = ty; r < 32; r += 8)
      t[r][tx] = W[(size_t)(k0 + r) * D + n0 + tx];
    __syncthreads();
    for (int r = ty; r < 32; r += 8)
      Wt[(size_t)(n0 + r) * D + k0 + tx] = f2bf(t[tx][r]);
  } else {
    int nb = gridDim.x - 128;
    for (int i = (blockIdx.x - 128) * 256 + threadIdx.x; i < ngz; i += nb * 256)
      gz[i] = 0;
  }
}

// ---------------- GEMM body: C_bf16[M,256] = bf16(A_f32) @ Bt ----------------
__device__ __forceinline__ void gemm_body(const float* __restrict__ A,
                                          const ushort* __restrict__ Bt,
                                          ushort* __restrict__ C, int M,
                                          int blk, int mtiles) {
  __shared__ ushort As[128 * 40];
  __shared__ ushort Bs[128 * 40];
  const int tid = threadIdx.x;
  const int bm = (blk % mtiles) * 128;
  const int bn = (blk / mtiles) * 128;
  const int wave = tid >> 6, lane = tid & 63;
  const int wm = wave & 1, wn = wave >> 1;
  const int lr = lane & 15;
  const int kg = lane >> 4;
  f32x4 acc[4][4];
#pragma unroll
  for (int m = 0; m < 4; ++m)
#pragma unroll
    for (int n = 0; n < 4; ++n) acc[m][n] = (f32x4){0.f, 0.f, 0.f, 0.f};

  for (int k0 = 0; k0 < D; k0 += 32) {
    __syncthreads();
#pragma unroll
    for (int c = 0; c < 4; ++c) {
      int linear = c * 256 + tid;
      int row = linear >> 3;
      int f4 = linear & 7;
      int gr = bm + row;
      float4 a = (gr < M) ? *(const float4*)(A + (size_t)gr * D + k0 + f4 * 4)
                          : make_float4(0.f, 0.f, 0.f, 0.f);
      ushort4 o;
      o.x = f2bf(a.x); o.y = f2bf(a.y); o.z = f2bf(a.z); o.w = f2bf(a.w);
      *(ushort4*)&As[row * 40 + f4 * 4] = o;
    }
#pragma unroll
    for (int c = 0; c < 2; ++c) {
      int linear = c * 256 + tid;
      int row = linear >> 2;
      int part = linear & 3;
      uint4 w4 = *(const uint4*)(Bt + (size_t)(bn + row) * D + k0 + part * 8);
      *(uint4*)&Bs[row * 40 + part * 8] = w4;
    }
    __syncthreads();
    short8 af[4], bfr[4];
#pragma unroll
    for (int m = 0; m < 4; ++m)
      af[m] = *(const short8*)&As[(wm * 64 + m * 16 + lr) * 40 + kg * 8];
#pragma unroll
    for (int n = 0; n < 4; ++n)
      bfr[n] = *(const short8*)&Bs[(wn * 64 + n * 16 + lr) * 40 + kg * 8];
#pragma unroll
    for (int m = 0; m < 4; ++m)
#pragma unroll
      for (int n = 0; n < 4; ++n)
        acc[m][n] = __builtin_amdgcn_mfma_f32_16x16x32_bf16(af[m], bfr[n], acc[m][n], 0, 0, 0);
  }

#pragma unroll
  for (int m = 0; m < 4; ++m)
#pragma unroll
    for (int j = 0; j < 4; ++j) {
      int gr = bm + wm * 64 + m * 16 + kg * 4 + j;
      if (gr < M) {
#pragma unroll
        for (int n = 0; n < 4; ++n) {
          int gc = bn + wn * 64 + n * 16 + lr;
          C[(size_t)gr * D + gc] = f2bf(acc[m][n][j]);
        }
      }
    }
}

// ---------------- pass A: bin edges by dst>>8 into dense bucket regions ----------------
__device__ __forceinline__ void binA_body(const int* __restrict__ src,
                                          const int* __restrict__ dst,
                                          const float* __restrict__ val, int E,
                                          int* __restrict__ gcur,
                                          int2* __restrict__ binned,
                                          int* __restrict__ ovfc, int4* __restrict__ ovf,
                                          int nbkt, int blk) {
  __shared__ int hist[200];
  __shared__ int base[200];
  const int tid = threadIdx.x;
  for (int i = tid; i < nbkt; i += 256) hist[i] = 0;
  __syncthreads();
  const int e0 = blk * CHUNK;
  const int e1 = min(E, e0 + CHUNK);
  for (int e = e0 + tid; e < e1; e += 256)
    atomicAdd(&hist[dst[e] >> 8], 1);
  __syncthreads();
  for (int i = tid; i < nbkt; i += 256) {
    int h = hist[i];
    base[i] = h ? atomicAdd(&gcur[i], h) : 0;
    hist[i] = 0;  // becomes local cursor
  }
  __syncthreads();
  for (int e = e0 + tid; e < e1; e += 256) {
    int d = dst[e];
    int s = src[e];
    int vb = __float_as_int(val[e]);
    int k = d >> 8;
    int pos = base[k] + atomicAdd(&hist[k], 1);
    if (pos < BCAP) {
      binned[(size_t)k * BCAP + pos] = make_int2(((d & 255) << 16) | s, vb);
    } else {
      int o = atomicAdd(ovfc, 1);
      if (o < OVFCAP) ovf[o] = make_int4(d, s, vb, 0);
    }
  }
}

// ---------------- fatA2: binA0 || binA1 || gemm0 -> H0 || gemm1 -> H1 ----------------
__global__ __launch_bounds__(256) void fatA2(
    const float* __restrict__ A, const ushort* __restrict__ Bt0, const ushort* __restrict__ Bt1,
    ushort* __restrict__ H0, ushort* __restrict__ H1, int M, int mtiles,
    const int* __restrict__ src0, const int* __restrict__ dst0, const float* __restrict__ val0,
    int E0, int* __restrict__ gcur0, int2* __restrict__ binned0, int* __restrict__ ovfc0,
    int4* __restrict__ ovf0,
    const int* __restrict__ src1, const int* __restrict__ dst1, const float* __restrict__ val1,
    int E1, int* __restrict__ gcur1, int2* __restrict__ binned1, int* __restrict__ ovfc1,
    int4* __restrict__ ovf1,
    int nbkt, int nbA0, int nbA1, int NGB) {
  const int bid = blockIdx.x;
  if (bid < nbA0)
    binA_body(src0, dst0, val0, E0, gcur0, binned0, ovfc0, ovf0, nbkt, bid);
  else if (bid < nbA0 + nbA1)
    binA_body(src1, dst1, val1, E1, gcur1, binned1, ovfc1, ovf1, nbkt, bid - nbA0);
  else if (bid < nbA0 + nbA1 + NGB)
    gemm_body(A, Bt0, H0, M, bid - nbA0 - nbA1, mtiles);
  else
    gemm_body(A, Bt1, H1, M, bid - nbA0 - nbA1 - NGB, mtiles);
}

// ---------------- pass B: bucket -> padded rows SORTED by src + per-tile quad offsets ----
// Tail quads zero-filled (src 0, val +0.0 => no-op). Per-row list sorted ascending by src;
// qseg[t][row] = first quad whose first-edge src >= t*tilespan, t = 0..TTILES.
__device__ __forceinline__ void passB_body(const int2* __restrict__ binned,
                                           const int* __restrict__ gcur,
                                           uint* __restrict__ padded,
                                           unsigned char* __restrict__ qseg,
                                           int* __restrict__ ovfc, int4* __restrict__ ovf,
                                           int b, int tilespan) {
  __shared__ int lcnt[256];
  __shared__ uint stage[256 * CAP_S];  // 60KB
  const int tid = threadIdx.x;
  lcnt[tid] = 0;
  __syncthreads();
  const int n = min(gcur[b], BCAP);
  const int2* bp = binned + (size_t)b * BCAP;
  for (int i = tid; i < n; i += 256) {
    int2 e = bp[i];
    int dlow = (e.x >> 16) & 255;
    int s = atomicAdd(&lcnt[dlow], 1);
    if (s < CAP_S) {
      float v = __int_as_float(e.y);
      stage[dlow * CAP_S + s] = (uint)(e.x & 0xFFFF) | ((uint)f2bf(v) << 16);
    } else {
      int o = atomicAdd(ovfc, 1);
      if (o < OVFCAP) ovf[o] = make_int4((b << 8) + dlow, e.x & 0xFFFF, e.y, 0);
    }
  }
  __syncthreads();
  // thread tid owns row (b*256 + tid)
  const int row = (b << 8) + tid;
  const int written = min(lcnt[tid], CAP_S);
  uint* sp = &stage[tid * CAP_S];
  // insertion sort by src (low 16 bits)
  for (int i = 1; i < written; ++i) {
    uint key = sp[i];
    uint ks = key & 0xFFFFu;
    int j = i - 1;
    while (j >= 0 && (sp[j] & 0xFFFFu) > ks) { sp[j + 1] = sp[j]; --j; }
    sp[j + 1] = key;
  }
  const int nq = (written + 3) >> 2;
  // per-tile quad boundaries (quad assigned to tile of its first edge)
  int qp = 0;
  for (int t = 0; t <= TTILES; ++t) {
    int lim = t * tilespan;
    while (qp < nq && (int)(sp[4 * qp] & 0xFFFFu) < lim) ++qp;
    qseg[(size_t)t * SEGSTRIDE + row] = (unsigned char)qp;
  }
  // zero tail + flush
  for (int s = written; s < (nq << 2); ++s) sp[s] = 0;
  uint4* dp = (uint4*)(padded + ((size_t)row << 6));
  const uint4* spq = (const uint4*)sp;
  for (int q = 0; q < nq; ++q) dp[q] = spq[q];
}

__global__ __launch_bounds__(256) void passBoth(
    const int2* __restrict__ binned0, const int* __restrict__ gcur0, uint* __restrict__ padded0,
    unsigned char* __restrict__ qseg0, int* __restrict__ ovfc0, int4* __restrict__ ovf0,
    const int2* __restrict__ binned1, const int* __restrict__ gcur1, uint* __restrict__ padded1,
    unsigned char* __restrict__ qseg1, int* __restrict__ ovfc1, int4* __restrict__ ovf1,
    int nbkt, int tilespan) {
  if (blockIdx.x < nbkt)
    passB_body(binned0, gcur0, padded0, qseg0, ovfc0, ovf0, blockIdx.x, tilespan);
  else
    passB_body(binned1, gcur1, padded1, qseg1, ovfc1, ovf1, blockIdx.x - nbkt, tilespan);
}

// ---------------- persistent lockstep sweep ----------------
__device__ __forceinline__ void edge_fma(uint e, const uint2* __restrict__ H2, int lane,
                                         float4& a) {
  uint2 h = H2[((size_t)(e & 0xFFFFu) << 6) + lane];
  float v = __uint_as_float(e & 0xFFFF0000u);
  a.x += v * bf_lo(h.x);
  a.y += v * bf_hi(h.x);
  a.z += v * bf_lo(h.y);
  a.w += v * bf_hi(h.y);
}

// Per tile: hoisted row bounds + 2-deep rotating first-quad meta prefetch across rows.
// Speculative (clamped) meta loads are branchless; consumed only when segment non-empty.
__device__ __forceinline__ void sweep_support(const ushort* __restrict__ H,
                                              const uint* __restrict__ padded,
                                              const unsigned char* __restrict__ qseg,
                                              int wid, int lane, float4* acc) {
  const uint2* H2 = (const uint2*)H;
  const uint4* p4 = (const uint4*)padded;
  for (int t = 0; t < TTILES; ++t) {
    uint bnd[RPW];
#pragma unroll
    for (int i = 0; i < RPW; ++i) {
      uint r = (uint)wid + (uint)i * NW;
      bnd[i] = (uint)qseg[(size_t)t * SEGSTRIDE + r] |
               ((uint)qseg[(size_t)(t + 1) * SEGSTRIDE + r] << 16);
    }
    uint4 mA, mB;
    {
      uint q = bnd[0] & 0xFFFFu, qe = bnd[0] >> 16;
      mA = p4[(((uint)wid) << 4) + (q < qe ? q : 0u)];
    }
    {
      uint q = bnd[1] & 0xFFFFu, qe = bnd[1] >> 16;
      mB = p4[(((uint)(wid + NW)) << 4) + (q < qe ? q : 0u)];
    }
#pragma unroll
    for (int i = 0; i < RPW; ++i) {
      uint q = bnd[i] & 0xFFFFu, qe = bnd[i] >> 16;
      uint4 m = (i & 1) ? mB : mA;
      if (i + 2 < RPW) {  // compile-time after unroll
        uint qn = bnd[i + 2] & 0xFFFFu, qen = bnd[i + 2] >> 16;
        uint4 mn = p4[(((uint)(wid + (i + 2) * NW)) << 4) + (qn < qen ? qn : 0u)];
        if (i & 1) mB = mn; else mA = mn;
      }
      if (q < qe) {
        const uint4* mp = p4 + (((size_t)(wid + i * NW)) << 4);
        for (;;) {
          edge_fma(m.x, H2, lane, acc[i]);
          edge_fma(m.y, H2, lane, acc[i]);
          edge_fma(m.z, H2, lane, acc[i]);
          edge_fma(m.w, H2, lane, acc[i]);
          if (++q >= qe) break;
          m = mp[q];
        }
      }
    }
  }
}

__global__ __launch_bounds__(256, 4) void spmm_sweep(
    const ushort* __restrict__ H0, const ushort* __restrict__ H1,
    const uint* __restrict__ padded0, const uint* __restrict__ padded1,
    const unsigned char* __restrict__ qseg0, const unsigned char* __restrict__ qseg1,
    float* __restrict__ out, const float* __restrict__ bias,
    const int* __restrict__ rowflag, int N) {
  const int wid = blockIdx.x * 4 + (threadIdx.x >> 6);
  const int lane = threadIdx.x & 63;
  float4 acc[RPW];  // shared across both supports: 52 VGPRs
#pragma unroll
  for (int i = 0; i < RPW; ++i) acc[i] = make_float4(0.f, 0.f, 0.f, 0.f);
  sweep_support(H0, padded0, qseg0, wid, lane, acc);
  sweep_support(H1, padded1, qseg1, wid, lane, acc);
  float4 bb = ((const float4*)bias)[lane];
#pragma unroll
  for (int i = 0; i < RPW; ++i) {
    int r = wid + i * NW;
    if (r < N) {
      float4* op = (float4*)(out + (size_t)r * D) + lane;
      float4 base = make_float4(0.f, 0.f, 0.f, 0.f);
      if (rowflag[r]) base = *op;  // overflow contributions pre-accumulated
      float4 o;
      o.x = fmaxf(acc[i].x + bb.x + base.x, 0.f);
      o.y = fmaxf(acc[i].y + bb.y + base.y, 0.f);
      o.z = fmaxf(acc[i].z + bb.z + base.z, 0.f);
      o.w = fmaxf(acc[i].w + bb.w + base.w, 0.f);
      *op = o;
    }
  }
}

// ---------------- overflow cleanup (expected 0 entries) ----------------
__global__ void ovf_zero(const int* __restrict__ ovfc0, const int4* __restrict__ ovf0,
                         const int* __restrict__ ovfc1, const int4* __restrict__ ovf1,
                         float* __restrict__ out, int* __restrict__ rowflag) {
  int n0 = min(*ovfc0, OVFCAP);
  int n1 = min(*ovfc1, OVFCAP);
  int w = (blockIdx.x * blockDim.x + threadIdx.x) >> 6;
  int lane = threadIdx.x & 63;
  int nw = (gridDim.x * blockDim.x) >> 6;
  for (int i = w; i < n0 + n1; i += nw) {
    int d = (i < n0) ? ovf0[i].x : ovf1[i - n0].x;
    if (lane == 0) rowflag[d] = 1;
    ((float4*)(out + (size_t)d * D))[lane] = make_float4(0.f, 0.f, 0.f, 0.f);
  }
}

__global__ void overflow_add(const int* __restrict__ ovfc, const int4* __restrict__ ovf,
                             const ushort* __restrict__ H, float* __restrict__ out) {
  int n = min(*ovfc, OVFCAP);
  int w = (blockIdx.x * blockDim.x + threadIdx.x) >> 6;
  int lane = threadIdx.x & 63;
  int nw = (gridDim.x * blockDim.x) >> 6;
  for (int i = w; i < n; i += nw) {
    int4 r = ovf[i];
    uint2 h = *((const uint2*)(H + (size_t)r.y * D) + lane);
    float v = __int_as_float(r.z);
    float* op = out + (size_t)r.x * D + (lane << 2);
    unsafeAtomicAdd(op + 0, v * bf_lo(h.x));
    unsafeAtomicAdd(op + 1, v * bf_hi(h.x));
    unsafeAtomicAdd(op + 2, v * bf_lo(h.y));
    unsafeAtomicAdd(op + 3, v * bf_hi(h.y));
  }
}

extern "C" void kernel_launch(void* const* d_in, const int* in_sizes, int n_in,
                              void* d_out, int out_size, void* d_ws, size_t ws_size,
                              hipStream_t stream) {
  const float* x    = (const float*)d_in[0];
  const float* W0   = (const float*)d_in[1];
  const float* W1   = (const float*)d_in[2];
  const float* b    = (const float*)d_in[3];
  const int*   src0 = (const int*)d_in[4];
  const int*   dst0 = (const int*)d_in[5];
  const float* val0 = (const float*)d_in[6];
  const int*   src1 = (const int*)d_in[7];
  const int*   dst1 = (const int*)d_in[8];
  const float* val1 = (const float*)d_in[9];
  float* out = (float*)d_out;

  const int N  = in_sizes[0] / D;       // 50000 (< 65536: src packs in 16 bits)
  const int E0 = in_sizes[4];
  const int E1 = in_sizes[7];
  const int nbkt = (N + 255) >> 8;      // 196 buckets of 256 rows
  const int nrows = nbkt << 8;          // 50176 padded rows (<= NW*RPW = 53248)
  const int tilespan = (N + TTILES - 1) / TTILES;  // 6250 src rows per tile (3.2 MB)

  const int mtiles = (N + 127) / 128;           // 391
  const int NGB = mtiles * 2;                   // 782 gemm blocks per support
  const int nbA0 = (E0 + CHUNK - 1) / CHUNK;    // 196
  const int nbA1 = (E1 + CHUNK - 1) / CHUNK;

  // ---- workspace layout (~108 MB) ----
  size_t off = 0;
  auto alloc = [&](size_t bytes) -> void* {
    void* p = (char*)d_ws + off;
    off = (off + bytes + 255) & ~(size_t)255;
    return p;
  };
  ushort* H0      = (ushort*)alloc((size_t)N * D * 2);        // 25.6 MB
  ushort* H1      = (ushort*)alloc((size_t)N * D * 2);        // 25.6 MB
  ushort* Wt0     = (ushort*)alloc((size_t)D * D * 2);
  ushort* Wt1     = (ushort*)alloc((size_t)D * D * 2);
  uint*   padded0 = (uint*)alloc((size_t)nrows * CAP * 4);    // 12.85 MB
  uint*   padded1 = (uint*)alloc((size_t)nrows * CAP * 4);    // 12.85 MB
  // gz region (all zeroed by prep): counters + rowflag + both qseg arrays
  const size_t qsegB = (size_t)2 * (TTILES + 1) * SEGSTRIDE;  // 0.96 MB
  const size_t gzB   = (size_t)(2 * nbkt + 2 + nrows) * 4 + qsegB;
  int*    gzall   = (int*)alloc(gzB);
  int4*   ovf0    = (int4*)alloc((size_t)OVFCAP * 16);
  int4*   ovf1    = (int4*)alloc((size_t)OVFCAP * 16);
  int2*   binned0 = (int2*)alloc((size_t)nbkt * BCAP * 8);    // 14.85 MB
  int2*   binned1 = (int2*)alloc((size_t)nbkt * BCAP * 8);    // 14.85 MB

  int* gcur0   = gzall;
  int* gcur1   = gzall + nbkt;
  int* ovfc0   = gzall + 2 * nbkt;
  int* ovfc1   = gzall + 2 * nbkt + 1;
  int* rowflag = gzall + 2 * nbkt + 2;
  unsigned char* qseg0 = (unsigned char*)(rowflag + nrows);
  unsigned char* qseg1 = qseg0 + (size_t)(TTILES + 1) * SEGSTRIDE;
  const int ngz = (int)(gzB / 4);

  // 1. prep: W transposes + zero counters/rowflag/qseg
  prep_kernel<<<192, 256, 0, stream>>>(W0, W1, Wt0, Wt1, gzall, ngz);
  // 2. fatA2: binA0 || binA1 || gemm0 -> H0 || gemm1 -> H1
  fatA2<<<nbA0 + nbA1 + 2 * NGB, 256, 0, stream>>>(
      x, Wt0, Wt1, H0, H1, N, mtiles,
      src0, dst0, val0, E0, gcur0, binned0, ovfc0, ovf0,
      src1, dst1, val1, E1, gcur1, binned1, ovfc1, ovf1,
      nbkt, nbA0, nbA1, NGB);
  // 3. passBoth: binned -> src-sorted padded rows + per-tile quad offsets
  passBoth<<<2 * nbkt, 256, 0, stream>>>(binned0, gcur0, padded0, qseg0, ovfc0, ovf0,
                                         binned1, gcur1, padded1, qseg1, ovfc1, ovf1,
                                         nbkt, tilespan);
  // 4. overflow slow path (expected empty): zero touched rows + flag, then add
  ovf_zero<<<16, 256, 0, stream>>>(ovfc0, ovf0, ovfc1, ovf1, out, rowflag);
  overflow_add<<<16, 256, 0, stream>>>(ovfc0, ovf0, H0, out);
  overflow_add<<<16, 256, 0, stream>>>(ovfc1, ovf1, H1, out);
  // 5. persistent lockstep sweep: out = relu(A0@H0 + A1@H1 + b [+ overflow])
  spmm_sweep<<<NW / 4, 256, 0, stream>>>(H0, H1, padded0, padded1, qseg0, qseg1,
                                         out, b, rowflag, N);
}

// Round 6
// 319.031 us; speedup vs baseline: 5.7874x; 2.1749x over previous
//
#include <hip/hip_runtime.h>

#define D 256
#define K2 512          // concatenated K for the output GEMM (two supports)
#define CAP 64          // padded row stride in slots (4B each)
#define CAP_S 60        // slots staged in LDS per row (62KB limit); rows deeper spill to ovf
#define OVFCAP 16384    // overflow edge list capacity
#define BCAP 10240      // entries per bucket region (mean 8163, +23 sigma)
#define CHUNK 8192      // edges per binning block

typedef __attribute__((ext_vector_type(8))) short short8;
typedef __attribute__((ext_vector_type(4))) float f32x4;

__device__ inline ushort f2bf(float f) {
  unsigned u = __float_as_uint(f);
  unsigned r = (u + 0x7FFF + ((u >> 16) & 1)) >> 16;  // RNE
  return (ushort)r;
}
__device__ inline float bf_lo(unsigned u) { return __uint_as_float(u << 16); }
__device__ inline float bf_hi(unsigned u) { return __uint_as_float(u & 0xFFFF0000u); }

// ---------------- prep: transpose W0|W1 into Wt[n][k0..511] + zero counters ----------------
__global__ __launch_bounds__(256) void prep_kernel(const float* __restrict__ W0,
                                                   const float* __restrict__ W1,
                                                   ushort* __restrict__ Wt,
                                                   int* __restrict__ gz, int ngz) {
  if (blockIdx.x < 128) {
    const int blk = blockIdx.x;
    const float* W = (blk >> 6) ? W1 : W0;
    const int koff = (blk >> 6) ? 256 : 0;
    __shared__ float t[32][33];
    int tx = threadIdx.x & 31, ty = threadIdx.x >> 5;
    int b = blk & 63;
    int k0 = (b & 7) * 32, n0 = (b >> 3) * 32;
    for (int r = ty; r < 32; r += 8)
      t[r][tx] = W[(size_t)(k0 + r) * D + n0 + tx];
    __syncthreads();
    for (int r = ty; r < 32; r += 8)
      Wt[(size_t)(n0 + r) * K2 + koff + k0 + tx] = f2bf(t[tx][r]);
  } else {
    int nb = gridDim.x - 128;
    for (int i = (blockIdx.x - 128) * 256 + threadIdx.x; i < ngz; i += nb * 256)
      gz[i] = 0;
  }
}

// ---------------- pass A: bin edges by dst>>8 into dense bucket regions ----------------
__device__ __forceinline__ void binA_body(const int* __restrict__ src,
                                          const int* __restrict__ dst,
                                          const float* __restrict__ val, int E,
                                          int* __restrict__ gcur,
                                          int2* __restrict__ binned,
                                          int* __restrict__ ovfc, int4* __restrict__ ovf,
                                          int nbkt, int blk) {
  __shared__ int hist[200];
  __shared__ int base[200];
  const int tid = threadIdx.x;
  for (int i = tid; i < nbkt; i += 256) hist[i] = 0;
  __syncthreads();
  const int e0 = blk * CHUNK;
  const int e1 = min(E, e0 + CHUNK);
  for (int e = e0 + tid; e < e1; e += 256)
    atomicAdd(&hist[dst[e] >> 8], 1);
  __syncthreads();
  for (int i = tid; i < nbkt; i += 256) {
    int h = hist[i];
    base[i] = h ? atomicAdd(&gcur[i], h) : 0;
    hist[i] = 0;  // becomes local cursor
  }
  __syncthreads();
  for (int e = e0 + tid; e < e1; e += 256) {
    int d = dst[e];
    int s = src[e];
    int vb = __float_as_int(val[e]);
    int k = d >> 8;
    int pos = base[k] + atomicAdd(&hist[k], 1);
    if (pos < BCAP) {
      binned[(size_t)k * BCAP + pos] = make_int2(((d & 255) << 16) | s, vb);
    } else {
      int o = atomicAdd(ovfc, 1);
      if (o < OVFCAP) ovf[o] = make_int4(d, s, vb, 0);
    }
  }
}

// ---------------- fat: binA0 || binA1 || x -> bf16 convert ----------------
__global__ __launch_bounds__(256) void fat_kernel(
    const float* __restrict__ x, ushort* __restrict__ Xb, int nq,
    const int* __restrict__ src0, const int* __restrict__ dst0, const float* __restrict__ val0,
    int E0, int* __restrict__ gcur0, int2* __restrict__ binned0, int* __restrict__ ovfc0,
    int4* __restrict__ ovf0,
    const int* __restrict__ src1, const int* __restrict__ dst1, const float* __restrict__ val1,
    int E1, int* __restrict__ gcur1, int2* __restrict__ binned1, int* __restrict__ ovfc1,
    int4* __restrict__ ovf1,
    int nbkt, int nbA0, int nbA1) {
  const int bid = blockIdx.x;
  if (bid < nbA0) {
    binA_body(src0, dst0, val0, E0, gcur0, binned0, ovfc0, ovf0, nbkt, bid);
  } else if (bid < nbA0 + nbA1) {
    binA_body(src1, dst1, val1, E1, gcur1, binned1, ovfc1, ovf1, nbkt, bid - nbA0);
  } else {
    const int nxb = gridDim.x - nbA0 - nbA1;
    for (int i = (bid - nbA0 - nbA1) * 256 + threadIdx.x; i < nq; i += nxb * 256) {
      float4 v = ((const float4*)x)[i];
      ushort4 o;
      o.x = f2bf(v.x); o.y = f2bf(v.y); o.z = f2bf(v.z); o.w = f2bf(v.w);
      ((ushort4*)Xb)[i] = o;
    }
  }
}

// ---------------- pass B: one block per bucket, LDS-staged padded build ----------------
// Tail quads are ZERO-FILLED so spmm can read whole quads without per-edge masking
// (zero slot => src 0, val +0.0 => contributes nothing).
__device__ __forceinline__ void passB_body(const int2* __restrict__ binned,
                                           const int* __restrict__ gcur,
                                           uint* __restrict__ padded,
                                           int* __restrict__ cnt,
                                           int* __restrict__ ovfc, int4* __restrict__ ovf,
                                           int b) {
  __shared__ int lcnt[256];
  __shared__ uint stage[256 * CAP_S];  // 60KB
  const int tid = threadIdx.x;
  lcnt[tid] = 0;
  __syncthreads();
  const int n = min(gcur[b], BCAP);
  const int2* bp = binned + (size_t)b * BCAP;
  for (int i = tid; i < n; i += 256) {
    int2 e = bp[i];
    int dlow = (e.x >> 16) & 255;
    int s = atomicAdd(&lcnt[dlow], 1);
    if (s < CAP_S) {
      float v = __int_as_float(e.y);
      stage[dlow * CAP_S + s] = (uint)(e.x & 0xFFFF) | ((uint)f2bf(v) << 16);
    } else {
      int o = atomicAdd(ovfc, 1);
      if (o < OVFCAP) ovf[o] = make_int4((b << 8) + dlow, e.x & 0xFFFF, e.y, 0);
    }
  }
  __syncthreads();
  // flush: thread tid owns row (b*256 + tid)
  const int row = (b << 8) + tid;
  const int written = min(lcnt[tid], CAP_S);
  cnt[row] = written;
  const int nq = (written + 3) >> 2;
  for (int s = written; s < (nq << 2); ++s) stage[tid * CAP_S + s] = 0;  // zero tail
  uint4* dp = (uint4*)(padded + ((size_t)row << 6));
  const uint4* sp = (const uint4*)&stage[tid * CAP_S];
  for (int q = 0; q < nq; ++q) dp[q] = sp[q];
}

__global__ __launch_bounds__(256) void passBoth(
    const int2* __restrict__ binned0, const int* __restrict__ gcur0, uint* __restrict__ padded0,
    int* __restrict__ cnt0, int* __restrict__ ovfc0, int4* __restrict__ ovf0,
    const int2* __restrict__ binned1, const int* __restrict__ gcur1, uint* __restrict__ padded1,
    int* __restrict__ cnt1, int* __restrict__ ovfc1, int4* __restrict__ ovf1, int nbkt) {
  if (blockIdx.x < nbkt)
    passB_body(binned0, gcur0, padded0, cnt0, ovfc0, ovf0, blockIdx.x);
  else
    passB_body(binned1, gcur1, padded1, cnt1, ovfc1, ovf1, blockIdx.x - nbkt);
}

// ---------------- gather core: paired-edge uint4 gathers, depth-2 chunk pipeline ----------
// Lanes 0-31 read edge A's 512B row (16B/lane), lanes 32-63 read edge B's row.
// Each lane accumulates 8 columns (lq*8 .. lq*8+7). Cross-half reduce at epilogue.
// Tail quads zero-filled by passB (src 0, val +0.0 => no-op).
__device__ __forceinline__ void gather_acc8(const ushort* __restrict__ Xb,
                                            const uint* __restrict__ padded,
                                            int row, int c, int lq, bool hi,
                                            float* acc) {
  const int nc = (c + 3) >> 2;
  if (nc <= 0) return;
  const uint4* ep4 = (const uint4*)(padded + ((size_t)row << 6));
  const uint4* Xb4 = (const uint4*)Xb;  // row r at Xb4[r << 5]

  uint4 h0a, h0b, h1a, h1b;
  float v0a, v0b, v1a, v1b;

#define GA_ISSUE(S, J)                                                  \
  do {                                                                  \
    uint4 m = ep4[(J)];                                                 \
    uint ea = hi ? m.y : m.x;                                           \
    uint eb = hi ? m.w : m.z;                                           \
    v##S##a = __uint_as_float(ea & 0xFFFF0000u);                        \
    v##S##b = __uint_as_float(eb & 0xFFFF0000u);                        \
    h##S##a = Xb4[((size_t)(ea & 0xFFFFu) << 5) + lq];                  \
    h##S##b = Xb4[((size_t)(eb & 0xFFFFu) << 5) + lq];                  \
  } while (0)

#define GA_COMP(S)                                                      \
  do {                                                                  \
    acc[0] += v##S##a * bf_lo(h##S##a.x);                               \
    acc[1] += v##S##a * bf_hi(h##S##a.x);                               \
    acc[2] += v##S##a * bf_lo(h##S##a.y);                               \
    acc[3] += v##S##a * bf_hi(h##S##a.y);                               \
    acc[4] += v##S##a * bf_lo(h##S##a.z);                               \
    acc[5] += v##S##a * bf_hi(h##S##a.z);                               \
    acc[6] += v##S##a * bf_lo(h##S##a.w);                               \
    acc[7] += v##S##a * bf_hi(h##S##a.w);                               \
    acc[0] += v##S##b * bf_lo(h##S##b.x);                               \
    acc[1] += v##S##b * bf_hi(h##S##b.x);                               \
    acc[2] += v##S##b * bf_lo(h##S##b.y);                               \
    acc[3] += v##S##b * bf_hi(h##S##b.y);                               \
    acc[4] += v##S##b * bf_lo(h##S##b.z);                               \
    acc[5] += v##S##b * bf_hi(h##S##b.z);                               \
    acc[6] += v##S##b * bf_lo(h##S##b.w);                               \
    acc[7] += v##S##b * bf_hi(h##S##b.w);                               \
  } while (0)

  GA_ISSUE(0, 0);
  if (nc > 1) GA_ISSUE(1, 1);
  int j = 0;
  for (; j + 1 < nc; j += 2) {
    GA_COMP(0);
    if (j + 2 < nc) GA_ISSUE(0, j + 2);
    GA_COMP(1);
    if (j + 3 < nc) GA_ISSUE(1, j + 3);
  }
  if (j < nc) GA_COMP(0);
#undef GA_ISSUE
#undef GA_COMP
}

// ---------------- spmmY: both supports gather from shared Xb -> Y bf16 [N, 512] ----------------
__global__ __launch_bounds__(256) void spmmY(const ushort* __restrict__ Xb,
                                             const uint* __restrict__ padded0,
                                             const int* __restrict__ cnt0,
                                             const uint* __restrict__ padded1,
                                             const int* __restrict__ cnt1,
                                             ushort* __restrict__ Y, int N) {
  const int row = blockIdx.x * 4 + (threadIdx.x >> 6);
  if (row >= N) return;
  const int lane = threadIdx.x & 63;
  const int lq = lane & 31;
  const bool hi = lane >= 32;
  float a0[8], a1[8];
#pragma unroll
  for (int k = 0; k < 8; ++k) { a0[k] = 0.f; a1[k] = 0.f; }
  gather_acc8(Xb, padded0, row, min(cnt0[row], CAP), lq, hi, a0);
  gather_acc8(Xb, padded1, row, min(cnt1[row], CAP), lq, hi, a1);
  // cross-half reduce (partner lane^32 holds the other edge-parity partial sums)
  float w[8];
#pragma unroll
  for (int k = 0; k < 8; ++k) {
    float r0 = a0[k] + __shfl_xor(a0[k], 32);
    float r1 = a1[k] + __shfl_xor(a1[k], 32);
    w[k] = hi ? r1 : r0;  // lanes<32 write support0 half, lanes>=32 support1 half
  }
  uint4 st;
  st.x = (uint)f2bf(w[0]) | ((uint)f2bf(w[1]) << 16);
  st.y = (uint)f2bf(w[2]) | ((uint)f2bf(w[3]) << 16);
  st.z = (uint)f2bf(w[4]) | ((uint)f2bf(w[5]) << 16);
  st.w = (uint)f2bf(w[6]) | ((uint)f2bf(w[7]) << 16);
  *(uint4*)(Y + (size_t)row * K2 + (hi ? 256 : 0) + lq * 8) = st;
}

// ---------------- overflow: serialized RMW into Y (expected 0 entries) ----------------
__global__ void ovf_serial(const int* __restrict__ ovfc0, const int4* __restrict__ ovf0,
                           const int* __restrict__ ovfc1, const int4* __restrict__ ovf1,
                           const ushort* __restrict__ Xb, ushort* __restrict__ Y) {
  int n0 = min(*ovfc0, OVFCAP);
  int n1 = min(*ovfc1, OVFCAP);
  const int tid = threadIdx.x;
  for (int i = 0; i < n0 + n1; ++i) {
    int4 r = (i < n0) ? ovf0[i] : ovf1[i - n0];
    int koff = (i < n0) ? 0 : 256;
    float v = __int_as_float(r.z);
    size_t yo = (size_t)r.x * K2 + koff + tid;
    float y = __uint_as_float((uint)Y[yo] << 16);
    float xv = __uint_as_float((uint)Xb[(size_t)r.y * D + tid] << 16);
    Y[yo] = f2bf(y + v * xv);
    __syncthreads();  // serialize entries (same-row collisions)
  }
}

// ---------------- output GEMM: out = relu(Y[M,512] @ Wt[256,512]^T + b) ----------------
__global__ __launch_bounds__(256) void gemm_out(const ushort* __restrict__ Y,
                                                const ushort* __restrict__ Wt,
                                                float* __restrict__ out,
                                                const float* __restrict__ bias,
                                                int M, int mtiles) {
  __shared__ ushort As[128 * 40];
  __shared__ ushort Bs[128 * 40];
  const int tid = threadIdx.x;
  const int blk = blockIdx.x;
  const int bm = (blk % mtiles) * 128;
  const int bn = (blk / mtiles) * 128;
  const int wave = tid >> 6, lane = tid & 63;
  const int wm = wave & 1, wn = wave >> 1;
  const int lr = lane & 15;
  const int kg = lane >> 4;
  f32x4 acc[4][4];
#pragma unroll
  for (int m = 0; m < 4; ++m)
#pragma unroll
    for (int n = 0; n < 4; ++n) acc[m][n] = (f32x4){0.f, 0.f, 0.f, 0.f};

  for (int k0 = 0; k0 < K2; k0 += 32) {
    __syncthreads();
#pragma unroll
    for (int c = 0; c < 2; ++c) {
      int linear = c * 256 + tid;
      int row = linear >> 2;
      int part = linear & 3;
      int gr = bm + row;
      uint4 a4 = make_uint4(0u, 0u, 0u, 0u);
      if (gr < M) a4 = *(const uint4*)(Y + (size_t)gr * K2 + k0 + part * 8);
      *(uint4*)&As[row * 40 + part * 8] = a4;
    }
#pragma unroll
    for (int c = 0; c < 2; ++c) {
      int linear = c * 256 + tid;
      int row = linear >> 2;
      int part = linear & 3;
      uint4 w4 = *(const uint4*)(Wt + (size_t)(bn + row) * K2 + k0 + part * 8);
      *(uint4*)&Bs[row * 40 + part * 8] = w4;
    }
    __syncthreads();
    short8 af[4], bfr[4];
#pragma unroll
    for (int m = 0; m < 4; ++m)
      af[m] = *(const short8*)&As[(wm * 64 + m * 16 + lr) * 40 + kg * 8];
#pragma unroll
    for (int n = 0; n < 4; ++n)
      bfr[n] = *(const short8*)&Bs[(wn * 64 + n * 16 + lr) * 40 + kg * 8];
#pragma unroll
    for (int m = 0; m < 4; ++m)
#pragma unroll
      for (int n = 0; n < 4; ++n)
        acc[m][n] = __builtin_amdgcn_mfma_f32_16x16x32_bf16(af[m], bfr[n], acc[m][n], 0, 0, 0);
  }

#pragma unroll
  for (int m = 0; m < 4; ++m)
#pragma unroll
    for (int j = 0; j < 4; ++j) {
      int gr = bm + wm * 64 + m * 16 + kg * 4 + j;
      if (gr < M) {
#pragma unroll
        for (int n = 0; n < 4; ++n) {
          int gc = bn + wn * 64 + n * 16 + lr;
          out[(size_t)gr * D + gc] = fmaxf(acc[m][n][j] + bias[gc], 0.f);
        }
      }
    }
}

extern "C" void kernel_launch(void* const* d_in, const int* in_sizes, int n_in,
                              void* d_out, int out_size, void* d_ws, size_t ws_size,
                              hipStream_t stream) {
  const float* x    = (const float*)d_in[0];
  const float* W0   = (const float*)d_in[1];
  const float* W1   = (const float*)d_in[2];
  const float* b    = (const float*)d_in[3];
  const int*   src0 = (const int*)d_in[4];
  const int*   dst0 = (const int*)d_in[5];
  const float* val0 = (const float*)d_in[6];
  const int*   src1 = (const int*)d_in[7];
  const int*   dst1 = (const int*)d_in[8];
  const float* val1 = (const float*)d_in[9];
  float* out = (float*)d_out;

  const int N  = in_sizes[0] / D;       // 50000 (< 65536: src packs in 16 bits)
  const int E0 = in_sizes[4];
  const int E1 = in_sizes[7];
  const int nbkt = (N + 255) >> 8;      // 196 buckets of 256 rows
  const int nrows = nbkt << 8;          // 50176 padded rows

  const int mtiles = (N + 127) / 128;           // 391
  const int NGB = mtiles * 2;                   // 782 gemm blocks (N=256 -> 2 n-tiles)
  const int nbA0 = (E0 + CHUNK - 1) / CHUNK;    // 196
  const int nbA1 = (E1 + CHUNK - 1) / CHUNK;
  const int NXB = 224;                          // x->bf16 convert blocks
  const int NPB = (N + 3) / 4;                  // 12500 spmm blocks

  // ---- workspace layout (~104 MB; Y overlays dead binned region) ----
  size_t off = 0;
  auto alloc = [&](size_t bytes) -> void* {
    void* p = (char*)d_ws + off;
    off = (off + bytes + 255) & ~(size_t)255;
    return p;
  };
  ushort* Xb      = (ushort*)alloc((size_t)N * D * 2);        // 25.6 MB
  ushort* Wt      = (ushort*)alloc((size_t)D * K2 * 2);       // 0.26 MB
  uint*   padded0 = (uint*)alloc((size_t)nrows * CAP * 4);    // 12.85 MB
  uint*   padded1 = (uint*)alloc((size_t)nrows * CAP * 4);    // 12.85 MB
  int*    cnt0    = (int*)alloc((size_t)nrows * 4);
  int*    cnt1    = (int*)alloc((size_t)nrows * 4);
  int*    gzall   = (int*)alloc((size_t)(2 * nbkt + 2) * 4);
  int4*   ovf0    = (int4*)alloc((size_t)OVFCAP * 16);
  int4*   ovf1    = (int4*)alloc((size_t)OVFCAP * 16);
  int2*   binned0 = (int2*)alloc((size_t)nbkt * BCAP * 8);    // 16.05 MB
  int2*   binned1 = (int2*)alloc((size_t)nbkt * BCAP * 8);    // 16.05 MB
  ushort* Y       = (ushort*)binned0;  // 51.2 MB; binned dead after passBoth

  int* gcur0 = gzall;
  int* gcur1 = gzall + nbkt;
  int* ovfc0 = gzall + 2 * nbkt;
  int* ovfc1 = gzall + 2 * nbkt + 1;

  // 1. prep: Wcat transpose + zero counters
  prep_kernel<<<130, 256, 0, stream>>>(W0, W1, Wt, gzall, 2 * nbkt + 2);
  // 2. fat: binA0 || binA1 || x->bf16
  fat_kernel<<<nbA0 + nbA1 + NXB, 256, 0, stream>>>(
      x, Xb, N * D / 4,
      src0, dst0, val0, E0, gcur0, binned0, ovfc0, ovf0,
      src1, dst1, val1, E1, gcur1, binned1, ovfc1, ovf1,
      nbkt, nbA0, nbA1);
  // 3. passBoth: binned -> padded + cnt for both supports
  passBoth<<<2 * nbkt, 256, 0, stream>>>(binned0, gcur0, padded0, cnt0, ovfc0, ovf0,
                                         binned1, gcur1, padded1, cnt1, ovfc1, ovf1, nbkt);
  // 4. spmm: Y[:,0:256] = A0 @ Xb ; Y[:,256:512] = A1 @ Xb  (paired-edge gathers)
  spmmY<<<NPB, 256, 0, stream>>>(Xb, padded0, cnt0, padded1, cnt1, Y, N);
  // 5. overflow slow path (expected empty), serialized RMW into Y
  ovf_serial<<<1, 256, 0, stream>>>(ovfc0, ovf0, ovfc1, ovf1, Xb, Y);
  // 6. output GEMM: out = relu(Y @ [W0;W1]^T + b)
  gemm_out<<<NGB, 256, 0, stream>>>(Y, Wt, out, b, N, mtiles);
}